// Round 1
// 731.604 us; speedup vs baseline: 1.0024x; 1.0024x over previous
//
#include <hip/hip_runtime.h>
#include <hip/hip_fp16.h>
#include <hip/hip_cooperative_groups.h>
#include <math.h>

namespace cg = cooperative_groups;

constexpr int B_ = 64;
constexpr int N_ = 4096;
constexpr int D_ = 256;
constexpr int NCH = 64;            // fallback path: chunks per batch row
constexpr int NPB = N_ / NCH;      // 64 rows per block
constexpr int NPW = NPB / 4;       // 16 rows per wave
constexpr int NSTEP = NPW / 4;     // fallback: 4 steps of 4 rows

// nontemporal float4 load (ext_vector to satisfy the builtin's type rules)
typedef float f4v __attribute__((ext_vector_type(4)));
__device__ __forceinline__ float4 nt_load4(const float4* p) {
    f4v v = __builtin_nontemporal_load((const f4v*)p);
    return make_float4(v.x, v.y, v.z, v.w);
}

// ---------------------------------------------------------------------------
// flag: is precision == I?  0 -> fast paths everywhere.
// ---------------------------------------------------------------------------
__global__ __launch_bounds__(256) void flag_kernel(const float* __restrict__ P,
                                                   int* __restrict__ flag) {
    __shared__ int sh[256];
    const int tid = threadIdx.x;
    int bad = 0;
    for (int i = tid; i < D_ * D_; i += 256) {
        const int r = i >> 8, c = i & 255;
        const float expect = (r == c) ? 1.0f : 0.0f;
        bad |= (P[i] != expect) ? 1 : 0;
    }
    sh[tid] = bad;
    __syncthreads();
    for (int s = 128; s > 0; s >>= 1) {
        if (tid < s) sh[tid] |= sh[tid + s];
        __syncthreads();
    }
    if (tid == 0) *flag = sh[0];
}

// ---------------------------------------------------------------------------
// Shared per-row score + online-softmax update (SLOW path; may barrier).
// Expects in scope: m[4], vr[4], runM, runS, tacc[4], flg, srows, wave, g, q, P.
// ---------------------------------------------------------------------------
#define SCORE_AND_UPDATE()                                                     \
    {                                                                          \
        float p_ = 0.f;                                                        \
        _Pragma("unroll")                                                      \
        for (int j = 0; j < 4; j++) {                                          \
            p_ += m[j].x * (vr[j].x - m[j].x);                                 \
            p_ += m[j].y * (vr[j].y - m[j].y);                                 \
            p_ += m[j].z * (vr[j].z - m[j].z);                                 \
            p_ += m[j].w * (vr[j].w - m[j].w);                                 \
        }                                                                      \
        p_ += __shfl_xor(p_, 1, 64);                                           \
        p_ += __shfl_xor(p_, 2, 64);                                           \
        p_ += __shfl_xor(p_, 4, 64);                                           \
        p_ += __shfl_xor(p_, 8, 64);                                           \
        float s_ = 0.5f * p_;                                                  \
        if (flg) { /* general P: s += 0.5*(||m||^2 - m^T P m) */               \
            __syncthreads();                                                   \
            _Pragma("unroll")                                                  \
            for (int jj = 0; jj < 2; jj++)                                     \
                _Pragma("unroll")                                              \
                for (int h = 0; h < 2; h++)                                    \
                    ((float4*)&srows[wave][g][0])[q * 2 + 32 * jj + h] =       \
                        m[jj * 2 + h];                                         \
            __syncthreads();                                                   \
            float dl = 0.f;                                                    \
            for (int k = 0; k < 16; k++) {                                     \
                const int d_ = q * 16 + k;                                     \
                const float md = srows[wave][g][d_];                           \
                float pm = 0.f;                                                \
                for (int e = 0; e < D_; e++)                                   \
                    pm += P[d_ * D_ + e] * srows[wave][g][e];                  \
                dl += md * (md - pm);                                          \
            }                                                                  \
            dl += __shfl_xor(dl, 1, 64);                                       \
            dl += __shfl_xor(dl, 2, 64);                                       \
            dl += __shfl_xor(dl, 4, 64);                                       \
            dl += __shfl_xor(dl, 8, 64);                                       \
            s_ += 0.5f * dl;                                                   \
        }                                                                      \
        const float newM_ = fmaxf(runM, s_);                                   \
        const float sc_ = __expf(runM - newM_);                                \
        const float e_  = __expf(s_ - newM_);                                  \
        runS = fmaf(runS, sc_, e_);                                            \
        _Pragma("unroll")                                                      \
        for (int j = 0; j < 4; j++) {                                          \
            tacc[j].x = fmaf(tacc[j].x, sc_, e_ * m[j].x);                     \
            tacc[j].y = fmaf(tacc[j].y, sc_, e_ * m[j].y);                     \
            tacc[j].z = fmaf(tacc[j].z, sc_, e_ * m[j].z);                     \
            tacc[j].w = fmaf(tacc[j].w, sc_, e_ * m[j].w);                     \
        }                                                                      \
        runM = newM_;                                                          \
    }

// FAST path: identity precision. No barriers, no LDS, pure register flow.
#define FAST_SCORE_UPDATE()                                                    \
    {                                                                          \
        float p_ = 0.f;                                                        \
        _Pragma("unroll")                                                      \
        for (int j = 0; j < 4; j++) {                                          \
            p_ += m[j].x * (vr[j].x - m[j].x);                                 \
            p_ += m[j].y * (vr[j].y - m[j].y);                                 \
            p_ += m[j].z * (vr[j].z - m[j].z);                                 \
            p_ += m[j].w * (vr[j].w - m[j].w);                                 \
        }                                                                      \
        p_ += __shfl_xor(p_, 1, 64);                                           \
        p_ += __shfl_xor(p_, 2, 64);                                           \
        p_ += __shfl_xor(p_, 4, 64);                                           \
        p_ += __shfl_xor(p_, 8, 64);                                           \
        const float s_ = 0.5f * p_;                                            \
        const float newM_ = fmaxf(runM, s_);                                   \
        const float sc_ = __expf(runM - newM_);                                \
        const float e_  = __expf(s_ - newM_);                                  \
        runS = fmaf(runS, sc_, e_);                                            \
        _Pragma("unroll")                                                      \
        for (int j = 0; j < 4; j++) {                                          \
            tacc[j].x = fmaf(tacc[j].x, sc_, e_ * m[j].x);                     \
            tacc[j].y = fmaf(tacc[j].y, sc_, e_ * m[j].y);                     \
            tacc[j].z = fmaf(tacc[j].z, sc_, e_ * m[j].z);                     \
            tacc[j].w = fmaf(tacc[j].w, sc_, e_ * m[j].w);                     \
        }                                                                      \
        runM = newM_;                                                          \
    }

// ---------------------------------------------------------------------------
// Persistent cooperative kernel: all 10 iterations in one launch.
// ---------------------------------------------------------------------------
template <bool USE_H, int PARTS_>
__global__ __launch_bounds__(256) void persistent_kernel(
        const float* __restrict__ means, const float* __restrict__ z0,
        const float* __restrict__ P, const int* __restrict__ flag,
        __half* __restrict__ mh, float* __restrict__ pT,
        float2* __restrict__ pS, float* __restrict__ out) {
    constexpr int GRID = 64 * PARTS_;
    constexpr int RPB = N_ / PARTS_;   // rows per block
    constexpr int RPW = RPB / 4;       // rows per wave
    constexpr int NSTEPS = RPW / 4;    // 4 rows (one per 16-lane group) per step
    cg::grid_group grid = cg::this_grid();

    const int gid = blockIdx.x, bb = gid / PARTS_, part = gid % PARTS_;
    const int tid = threadIdx.x, wave = tid >> 6, lane = tid & 63;
    const int q = lane & 15, g = lane >> 4;

    __shared__ __align__(16) float vsh[D_];
    __shared__ __align__(16) float shbuf[4][D_];
    __shared__ __align__(16) float srows[4][4][D_];   // slow path only
    __shared__ __align__(16) float zsh[D_];
    __shared__ float wM[4], wS[4];

    const int flg = *flag;

    // v0 = (P+P^T) z0  (fast path 2*z0)
    {
        const float zd = z0[bb * D_ + tid];
        if (!flg) {
            vsh[tid] = 2.f * zd;
        } else {
            zsh[tid] = zd;
            __syncthreads();
            float vv = 0.f;
            for (int e = 0; e < D_; e++)
                vv += (P[tid * D_ + e] + P[e * D_ + tid]) * zsh[e];
            vsh[tid] = vv;
        }
        __syncthreads();
    }

    const size_t wrowbase = (size_t)bb * N_ + (size_t)part * RPB + (size_t)wave * RPW;

    for (int t = 0; t < 10; t++) {
        float4 vr[4];   // vr[jj*2+h] covers d = q*8 + 128*jj + 4*h
        #pragma unroll
        for (int jj = 0; jj < 2; jj++)
            #pragma unroll
            for (int h = 0; h < 2; h++)
                vr[jj * 2 + h] = ((const float4*)vsh)[q * 2 + 32 * jj + h];

        float runM = -INFINITY, runS = 0.f;
        float4 tacc[4];
        #pragma unroll
        for (int j = 0; j < 4; j++) tacc[j] = make_float4(0.f, 0.f, 0.f, 0.f);

        if (!flg) {
            // ================= FAST PATH: no barriers, manual prefetch ====
            if (USE_H && t > 0) {
                const __half* wb = mh + wrowbase * D_;
                // prologue: load row for step 0
                float4 r0 = ((const float4*)(wb + (size_t)g * D_))[q];
                float4 r1 = ((const float4*)(wb + (size_t)g * D_))[q + 16];
                #pragma unroll 2
                for (int step = 0; step < NSTEPS; step++) {
                    // issue next row's loads before consuming current row
                    const int pr = ((step + 1 < NSTEPS) ? step + 1 : step) * 4 + g;
                    const __half* rpn = wb + (size_t)pr * D_;
                    const float4 n0 = ((const float4*)rpn)[q];
                    const float4 n1 = ((const float4*)rpn)[q + 16];
                    float4 m[4];
                    {
                        const __half2* h0 = (const __half2*)&r0;
                        const float2 f0 = __half22float2(h0[0]);
                        const float2 f1 = __half22float2(h0[1]);
                        const float2 f2 = __half22float2(h0[2]);
                        const float2 f3 = __half22float2(h0[3]);
                        m[0] = make_float4(f0.x, f0.y, f1.x, f1.y);
                        m[1] = make_float4(f2.x, f2.y, f3.x, f3.y);
                        const __half2* h1 = (const __half2*)&r1;
                        const float2 g0 = __half22float2(h1[0]);
                        const float2 g1 = __half22float2(h1[1]);
                        const float2 g2 = __half22float2(h1[2]);
                        const float2 g3 = __half22float2(h1[3]);
                        m[2] = make_float4(g0.x, g0.y, g1.x, g1.y);
                        m[3] = make_float4(g2.x, g2.y, g3.x, g3.y);
                    }
                    FAST_SCORE_UPDATE()
                    r0 = n0; r1 = n1;
                }
            } else {
                const float* wb = means + wrowbase * D_;
                // prologue: load row for step 0 (nontemporal: one-shot f32
                // stream; keep the f16 copy resident in L3 instead)
                float4 m[4];
                {
                    const float4* rp = (const float4*)(wb + (size_t)g * D_);
                    m[0] = nt_load4(rp + q * 2);
                    m[1] = nt_load4(rp + q * 2 + 1);
                    m[2] = nt_load4(rp + q * 2 + 32);
                    m[3] = nt_load4(rp + q * 2 + 33);
                }
                #pragma unroll 2
                for (int step = 0; step < NSTEPS; step++) {
                    const int pr = ((step + 1 < NSTEPS) ? step + 1 : step) * 4 + g;
                    const float4* rpn = (const float4*)(wb + (size_t)pr * D_);
                    const float4 n0 = nt_load4(rpn + q * 2);
                    const float4 n1 = nt_load4(rpn + q * 2 + 1);
                    const float4 n2 = nt_load4(rpn + q * 2 + 32);
                    const float4 n3 = nt_load4(rpn + q * 2 + 33);
                    if (USE_H && t == 0) {
                        const int r = step * 4 + g;
                        __half* hp = mh + (wrowbase + r) * D_;
                        #pragma unroll
                        for (int jj = 0; jj < 2; jj++) {
                            union { uint4 u4; __half2 h2[4]; } pk;
                            pk.h2[0] = __floats2half2_rn(m[jj*2].x,   m[jj*2].y);
                            pk.h2[1] = __floats2half2_rn(m[jj*2].z,   m[jj*2].w);
                            pk.h2[2] = __floats2half2_rn(m[jj*2+1].x, m[jj*2+1].y);
                            pk.h2[3] = __floats2half2_rn(m[jj*2+1].z, m[jj*2+1].w);
                            *(uint4*)(hp + q * 8 + 128 * jj) = pk.u4;
                        }
                    }
                    FAST_SCORE_UPDATE()
                    m[0] = n0; m[1] = n1; m[2] = n2; m[3] = n3;
                }
            }
        } else {
            // ================= SLOW PATH: general P (original code) =======
            if (USE_H && t > 0) {
                for (int step = 0; step < NSTEPS; step++) {
                    const int r = step * 4 + g;
                    const __half* rp = mh + (wrowbase + r) * D_;
                    float4 m[4];
                    #pragma unroll
                    for (int jj = 0; jj < 2; jj++) {
                        float4 raw = ((const float4*)rp)[q + 16 * jj];   // 8 halves
                        const __half2* hp2 = (const __half2*)&raw;
                        const float2 f0 = __half22float2(hp2[0]);
                        const float2 f1 = __half22float2(hp2[1]);
                        const float2 f2 = __half22float2(hp2[2]);
                        const float2 f3 = __half22float2(hp2[3]);
                        m[jj * 2 + 0] = make_float4(f0.x, f0.y, f1.x, f1.y);
                        m[jj * 2 + 1] = make_float4(f2.x, f2.y, f3.x, f3.y);
                    }
                    SCORE_AND_UPDATE()
                }
            } else {
                for (int step = 0; step < NSTEPS; step++) {
                    const int r = step * 4 + g;
                    const float* rp = means + (wrowbase + r) * D_;
                    float4 m[4];
                    #pragma unroll
                    for (int jj = 0; jj < 2; jj++)
                        #pragma unroll
                        for (int h = 0; h < 2; h++)
                            m[jj * 2 + h] = ((const float4*)rp)[q * 2 + 32 * jj + h];
                    if (USE_H && t == 0) {
                        __half* hp = mh + (wrowbase + r) * D_;
                        #pragma unroll
                        for (int jj = 0; jj < 2; jj++) {
                            union { uint4 u4; __half2 h2[4]; } pk;
                            pk.h2[0] = __floats2half2_rn(m[jj*2].x,   m[jj*2].y);
                            pk.h2[1] = __floats2half2_rn(m[jj*2].z,   m[jj*2].w);
                            pk.h2[2] = __floats2half2_rn(m[jj*2+1].x, m[jj*2+1].y);
                            pk.h2[3] = __floats2half2_rn(m[jj*2+1].z, m[jj*2+1].w);
                            *(uint4*)(hp + q * 8 + 128 * jj) = pk.u4;
                        }
                    }
                    SCORE_AND_UPDATE()
                }
            }
        }

        // ---- epilogue: combine 4 lane-groups (xor 16/32), then 4 waves ----
        float Mw = runM;
        Mw = fmaxf(Mw, __shfl_xor(Mw, 16, 64));
        Mw = fmaxf(Mw, __shfl_xor(Mw, 32, 64));
        const float aw = __expf(runM - Mw);
        float Sa = runS * aw;
        Sa += __shfl_xor(Sa, 16, 64);
        Sa += __shfl_xor(Sa, 32, 64);
        #pragma unroll
        for (int j = 0; j < 4; j++) {
            tacc[j].x *= aw; tacc[j].y *= aw; tacc[j].z *= aw; tacc[j].w *= aw;
            tacc[j].x += __shfl_xor(tacc[j].x, 16, 64);
            tacc[j].y += __shfl_xor(tacc[j].y, 16, 64);
            tacc[j].z += __shfl_xor(tacc[j].z, 16, 64);
            tacc[j].w += __shfl_xor(tacc[j].w, 16, 64);
            tacc[j].x += __shfl_xor(tacc[j].x, 32, 64);
            tacc[j].y += __shfl_xor(tacc[j].y, 32, 64);
            tacc[j].z += __shfl_xor(tacc[j].z, 32, 64);
            tacc[j].w += __shfl_xor(tacc[j].w, 32, 64);
        }
        if (lane < 16) {
            #pragma unroll
            for (int j = 0; j < 4; j++)
                ((float4*)shbuf[wave])[q * 2 + 32 * (j >> 1) + (j & 1)] = tacc[j];
        }
        if (lane == 0) { wM[wave] = Mw; wS[wave] = Sa; }
        __syncthreads();
        const float Mb = fmaxf(fmaxf(wM[0], wM[1]), fmaxf(wM[2], wM[3]));
        const float a0 = __expf(wM[0] - Mb), a1 = __expf(wM[1] - Mb),
                    a2 = __expf(wM[2] - Mb), a3 = __expf(wM[3] - Mb);
        const float Tc = a0 * shbuf[0][tid] + a1 * shbuf[1][tid] +
                         a2 * shbuf[2][tid] + a3 * shbuf[3][tid];
        const int buf = t & 1;
        pT[((size_t)buf * GRID + gid) * D_ + tid] = Tc;
        if (tid == 0)
            pS[buf * GRID + gid] = make_float2(
                Mb, a0 * wS[0] + a1 * wS[1] + a2 * wS[2] + a3 * wS[3]);

        grid.sync();

        // ---- combine PARTS_ partials for my bb (redundant per part) ----
        float Mg = -INFINITY;
        float2 stl[PARTS_];
        #pragma unroll
        for (int pI = 0; pI < PARTS_; pI++) {
            stl[pI] = pS[buf * GRID + bb * PARTS_ + pI];
            Mg = fmaxf(Mg, stl[pI].x);
        }
        float Sg = 0.f, accg = 0.f;
        #pragma unroll
        for (int pI = 0; pI < PARTS_; pI++) {
            const float a = __expf(stl[pI].x - Mg);
            Sg += a * stl[pI].y;
            accg += a * pT[((size_t)buf * GRID + bb * PARTS_ + pI) * D_ + tid];
        }
        const float zv = accg / Sg;
        if (t == 9) {
            if (part == 0) out[bb * D_ + tid] = zv;
        } else {
            if (!flg) {
                vsh[tid] = 2.f * zv;
            } else {
                zsh[tid] = zv;
                __syncthreads();
                float vv = 0.f;
                for (int e = 0; e < D_; e++)
                    vv += (P[tid * D_ + e] + P[e * D_ + tid]) * zsh[e];
                vsh[tid] = vv;
            }
            __syncthreads();
        }
    }
}

// ===========================================================================
// Fallback multi-kernel path (round-4, proven) — used if workspace or
// cooperative occupancy is insufficient.
// ===========================================================================
__global__ __launch_bounds__(256) void vcalc_kernel(const float* __restrict__ P,
                                                    const float* __restrict__ z,
                                                    const int* __restrict__ flag,
                                                    float* __restrict__ v) {
    __shared__ float zsh[D_];
    const int b = blockIdx.x, d = threadIdx.x;
    const float zd = z[b * D_ + d];
    if (*flag == 0) {
        v[b * D_ + d] = 2.0f * zd;
        return;
    }
    zsh[d] = zd;
    __syncthreads();
    float acc = 0.f;
    for (int e = 0; e < D_; e++)
        acc += (P[d * D_ + e] + P[e * D_ + d]) * zsh[e];
    v[b * D_ + d] = acc;
}

template <bool WRITE_H>
__global__ __launch_bounds__(256) void fused_f32_kernel(const float* __restrict__ means,
                                                        const float* __restrict__ v,
                                                        const float* __restrict__ P,
                                                        const int* __restrict__ flag,
                                                        __half* __restrict__ mh,
                                                        float* __restrict__ Tbuf,
                                                        float2* __restrict__ stats) {
    const int b = blockIdx.y, chunk = blockIdx.x;
    const int tid = threadIdx.x, wave = tid >> 6, lane = tid & 63;
    const int q = lane & 15, g = lane >> 4;
    __shared__ __align__(16) float vsh[D_];
    __shared__ __align__(16) float shbuf[4][D_];
    __shared__ __align__(16) float srows[4][4][D_];
    __shared__ float wM[4], wS[4];
    vsh[tid] = v[b * D_ + tid];
    __syncthreads();
    float4 vr[4];
    #pragma unroll
    for (int jj = 0; jj < 2; jj++)
        #pragma unroll
        for (int h = 0; h < 2; h++)
            vr[jj * 2 + h] = ((const float4*)vsh)[q * 2 + 32 * jj + h];
    const int flg = *flag;

    float runM = -INFINITY, runS = 0.f;
    float4 tacc[4];
    #pragma unroll
    for (int j = 0; j < 4; j++) tacc[j] = make_float4(0.f, 0.f, 0.f, 0.f);

    const size_t rowbase = (size_t)b * N_ + (size_t)chunk * NPB + (size_t)wave * NPW;

    for (int step = 0; step < NSTEP; step++) {
        const int r = step * 4 + g;
        const float* rp = means + (rowbase + r) * D_;
        float4 m[4];
        #pragma unroll
        for (int jj = 0; jj < 2; jj++)
            #pragma unroll
            for (int h = 0; h < 2; h++)
                m[jj * 2 + h] = ((const float4*)rp)[q * 2 + 32 * jj + h];
        if (WRITE_H) {
            __half* hp = mh + (rowbase + r) * D_;
            #pragma unroll
            for (int jj = 0; jj < 2; jj++) {
                union { uint4 u4; __half2 h2[4]; } pk;
                pk.h2[0] = __floats2half2_rn(m[jj*2].x,   m[jj*2].y);
                pk.h2[1] = __floats2half2_rn(m[jj*2].z,   m[jj*2].w);
                pk.h2[2] = __floats2half2_rn(m[jj*2+1].x, m[jj*2+1].y);
                pk.h2[3] = __floats2half2_rn(m[jj*2+1].z, m[jj*2+1].w);
                *(uint4*)(hp + q * 8 + 128 * jj) = pk.u4;
            }
        }
        SCORE_AND_UPDATE()
    }

    float Mw = runM;
    Mw = fmaxf(Mw, __shfl_xor(Mw, 16, 64));
    Mw = fmaxf(Mw, __shfl_xor(Mw, 32, 64));
    const float aw = __expf(runM - Mw);
    float Sa = runS * aw;
    Sa += __shfl_xor(Sa, 16, 64);
    Sa += __shfl_xor(Sa, 32, 64);
    #pragma unroll
    for (int j = 0; j < 4; j++) {
        tacc[j].x *= aw; tacc[j].y *= aw; tacc[j].z *= aw; tacc[j].w *= aw;
        tacc[j].x += __shfl_xor(tacc[j].x, 16, 64);
        tacc[j].y += __shfl_xor(tacc[j].y, 16, 64);
        tacc[j].z += __shfl_xor(tacc[j].z, 16, 64);
        tacc[j].w += __shfl_xor(tacc[j].w, 16, 64);
        tacc[j].x += __shfl_xor(tacc[j].x, 32, 64);
        tacc[j].y += __shfl_xor(tacc[j].y, 32, 64);
        tacc[j].z += __shfl_xor(tacc[j].z, 32, 64);
        tacc[j].w += __shfl_xor(tacc[j].w, 32, 64);
    }
    if (lane < 16) {
        #pragma unroll
        for (int j = 0; j < 4; j++)
            ((float4*)shbuf[wave])[q * 2 + 32 * (j >> 1) + (j & 1)] = tacc[j];
    }
    if (lane == 0) { wM[wave] = Mw; wS[wave] = Sa; }
    __syncthreads();
    const float Mb = fmaxf(fmaxf(wM[0], wM[1]), fmaxf(wM[2], wM[3]));
    const float a0 = __expf(wM[0] - Mb), a1 = __expf(wM[1] - Mb),
                a2 = __expf(wM[2] - Mb), a3 = __expf(wM[3] - Mb);
    const float Tc = a0 * shbuf[0][tid] + a1 * shbuf[1][tid] +
                     a2 * shbuf[2][tid] + a3 * shbuf[3][tid];
    Tbuf[((size_t)(b * NCH + chunk)) * D_ + tid] = Tc;
    if (tid == 0)
        stats[b * NCH + chunk] = make_float2(
            Mb, a0 * wS[0] + a1 * wS[1] + a2 * wS[2] + a3 * wS[3]);
}

__global__ __launch_bounds__(256) void fused_f16_kernel(const __half* __restrict__ mh,
                                                        const float* __restrict__ v,
                                                        const float* __restrict__ P,
                                                        const int* __restrict__ flag,
                                                        float* __restrict__ Tbuf,
                                                        float2* __restrict__ stats) {
    const int b = blockIdx.y, chunk = blockIdx.x;
    const int tid = threadIdx.x, wave = tid >> 6, lane = tid & 63;
    const int q = lane & 15, g = lane >> 4;
    __shared__ __align__(16) float vsh[D_];
    __shared__ __align__(16) float shbuf[4][D_];
    __shared__ __align__(16) float srows[4][4][D_];
    __shared__ float wM[4], wS[4];
    vsh[tid] = v[b * D_ + tid];
    __syncthreads();
    float4 vr[4];
    #pragma unroll
    for (int jj = 0; jj < 2; jj++)
        #pragma unroll
        for (int h = 0; h < 2; h++)
            vr[jj * 2 + h] = ((const float4*)vsh)[q * 2 + 32 * jj + h];
    const int flg = *flag;

    float runM = -INFINITY, runS = 0.f;
    float4 tacc[4];
    #pragma unroll
    for (int j = 0; j < 4; j++) tacc[j] = make_float4(0.f, 0.f, 0.f, 0.f);

    const size_t rowbase = (size_t)b * N_ + (size_t)chunk * NPB + (size_t)wave * NPW;

    for (int step = 0; step < NSTEP; step++) {
        const int r = step * 4 + g;
        const __half* rp = mh + (rowbase + r) * D_;
        float4 m[4];
        #pragma unroll
        for (int jj = 0; jj < 2; jj++) {
            float4 raw = ((const float4*)rp)[q + 16 * jj];
            const __half2* hp2 = (const __half2*)&raw;
            const float2 f0 = __half22float2(hp2[0]);
            const float2 f1 = __half22float2(hp2[1]);
            const float2 f2 = __half22float2(hp2[2]);
            const float2 f3 = __half22float2(hp2[3]);
            m[jj * 2 + 0] = make_float4(f0.x, f0.y, f1.x, f1.y);
            m[jj * 2 + 1] = make_float4(f2.x, f2.y, f3.x, f3.y);
        }
        SCORE_AND_UPDATE()
    }

    float Mw = runM;
    Mw = fmaxf(Mw, __shfl_xor(Mw, 16, 64));
    Mw = fmaxf(Mw, __shfl_xor(Mw, 32, 64));
    const float aw = __expf(runM - Mw);
    float Sa = runS * aw;
    Sa += __shfl_xor(Sa, 16, 64);
    Sa += __shfl_xor(Sa, 32, 64);
    #pragma unroll
    for (int j = 0; j < 4; j++) {
        tacc[j].x *= aw; tacc[j].y *= aw; tacc[j].z *= aw; tacc[j].w *= aw;
        tacc[j].x += __shfl_xor(tacc[j].x, 16, 64);
        tacc[j].y += __shfl_xor(tacc[j].y, 16, 64);
        tacc[j].z += __shfl_xor(tacc[j].z, 16, 64);
        tacc[j].w += __shfl_xor(tacc[j].w, 16, 64);
        tacc[j].x += __shfl_xor(tacc[j].x, 32, 64);
        tacc[j].y += __shfl_xor(tacc[j].y, 32, 64);
        tacc[j].z += __shfl_xor(tacc[j].z, 32, 64);
        tacc[j].w += __shfl_xor(tacc[j].w, 32, 64);
    }
    if (lane < 16) {
        #pragma unroll
        for (int j = 0; j < 4; j++)
            ((float4*)shbuf[wave])[q * 2 + 32 * (j >> 1) + (j & 1)] = tacc[j];
    }
    if (lane == 0) { wM[wave] = Mw; wS[wave] = Sa; }
    __syncthreads();
    const float Mb = fmaxf(fmaxf(wM[0], wM[1]), fmaxf(wM[2], wM[3]));
    const float a0 = __expf(wM[0] - Mb), a1 = __expf(wM[1] - Mb),
                a2 = __expf(wM[2] - Mb), a3 = __expf(wM[3] - Mb);
    const float Tc = a0 * shbuf[0][tid] + a1 * shbuf[1][tid] +
                     a2 * shbuf[2][tid] + a3 * shbuf[3][tid];
    Tbuf[((size_t)(b * NCH + chunk)) * D_ + tid] = Tc;
    if (tid == 0)
        stats[b * NCH + chunk] = make_float2(
            Mb, a0 * wS[0] + a1 * wS[1] + a2 * wS[2] + a3 * wS[3]);
}

__global__ __launch_bounds__(256) void combine_kernel(const float* __restrict__ Tbuf,
                                                      const float2* __restrict__ stats,
                                                      const float* __restrict__ P,
                                                      const int* __restrict__ flag,
                                                      float* __restrict__ v,
                                                      float* __restrict__ out) {
    const int b = blockIdx.x, d = threadIdx.x;
    __shared__ float Msh[NCH], Ssh[NCH];
    __shared__ float zsh[D_];
    if (d < NCH) {
        const float2 st = stats[b * NCH + d];
        Msh[d] = st.x; Ssh[d] = st.y;
    }
    __syncthreads();
    float M = -INFINITY;
    for (int c = 0; c < NCH; c++) M = fmaxf(M, Msh[c]);
    float S = 0.f, acc = 0.f;
    for (int c = 0; c < NCH; c++) {
        const float a = __expf(Msh[c] - M);
        S += a * Ssh[c];
        acc += a * Tbuf[((size_t)(b * NCH + c)) * D_ + d];
    }
    const float z = acc / S;
    if (out) out[b * D_ + d] = z;
    if (*flag == 0) {
        v[b * D_ + d] = 2.0f * z;
        return;
    }
    zsh[d] = z;
    __syncthreads();
    float vv = 0.f;
    for (int e = 0; e < D_; e++)
        vv += (P[d * D_ + e] + P[e * D_ + d]) * zsh[e];
    v[b * D_ + d] = vv;
}

extern "C" void kernel_launch(void* const* d_in, const int* in_sizes, int n_in,
                              void* d_out, int out_size, void* d_ws, size_t ws_size,
                              hipStream_t stream) {
    // inputs: 0=x (unused), 1=z, 2=means, 3=precision, 4=iterations(=10)
    const float* z0    = (const float*)d_in[1];
    const float* means = (const float*)d_in[2];
    const float* P     = (const float*)d_in[3];
    float* out = (float*)d_out;

    char* ws = (char*)d_ws;
    size_t off = 0;
    int*    flag  = (int*)ws;                     off = 256;
    float*  v     = (float*)(ws + off);           off += (size_t)B_ * D_ * 4;
    float*  Tbuf  = (float*)(ws + off);           off += (size_t)B_ * NCH * D_ * 4;
    float2* stats = (float2*)(ws + off);          off += (size_t)B_ * NCH * 8;
    off = (off + 255) & ~(size_t)255;
    float*  pT    = (float*)(ws + off);           off += 2ull * 1024 * D_ * 4;
    float2* pS    = (float2*)(ws + off);          off += 2ull * 1024 * 8;
    off = (off + 255) & ~(size_t)255;
    __half* mh    = (__half*)(ws + off);
    const size_t coop_need  = off;                               // ~6.3 MiB
    const size_t full_need  = off + (size_t)B_ * N_ * D_ * 2;    // + 128 MiB
    const bool use_h = (ws_size >= full_need);
    const bool ws_ok = (ws_size >= coop_need);

    flag_kernel<<<dim3(1), dim3(256), 0, stream>>>(P, flag);

    // ---- cooperative persistent path (preferred) ----
    if (ws_ok) {
        void* args[] = {(void*)&means, (void*)&z0, (void*)&P, (void*)&flag,
                        (void*)&mh, (void*)&pT, (void*)&pS, (void*)&out};
        int nb = 0;
        if (use_h) {
            if (hipOccupancyMaxActiveBlocksPerMultiprocessor(
                    &nb, persistent_kernel<true, 16>, 256, 0) == hipSuccess && nb >= 4) {
                if (hipLaunchCooperativeKernel(persistent_kernel<true, 16>,
                        dim3(1024), dim3(256), args, 0, stream) == hipSuccess)
                    return;
            }
            nb = 0;
            if (hipOccupancyMaxActiveBlocksPerMultiprocessor(
                    &nb, persistent_kernel<true, 8>, 256, 0) == hipSuccess && nb >= 2) {
                if (hipLaunchCooperativeKernel(persistent_kernel<true, 8>,
                        dim3(512), dim3(256), args, 0, stream) == hipSuccess)
                    return;
            }
        } else {
            if (hipOccupancyMaxActiveBlocksPerMultiprocessor(
                    &nb, persistent_kernel<false, 16>, 256, 0) == hipSuccess && nb >= 4) {
                if (hipLaunchCooperativeKernel(persistent_kernel<false, 16>,
                        dim3(1024), dim3(256), args, 0, stream) == hipSuccess)
                    return;
            }
            nb = 0;
            if (hipOccupancyMaxActiveBlocksPerMultiprocessor(
                    &nb, persistent_kernel<false, 8>, 256, 0) == hipSuccess && nb >= 2) {
                if (hipLaunchCooperativeKernel(persistent_kernel<false, 8>,
                        dim3(512), dim3(256), args, 0, stream) == hipSuccess)
                    return;
            }
        }
    }

    // ---- fallback multi-kernel path (round-4) ----
    vcalc_kernel<<<dim3(B_), dim3(256), 0, stream>>>(P, z0, flag, v);
    if (use_h) {
        fused_f32_kernel<true><<<dim3(NCH, B_), dim3(256), 0, stream>>>(
            means, v, P, flag, mh, Tbuf, stats);
        combine_kernel<<<dim3(B_), dim3(256), 0, stream>>>(Tbuf, stats, P, flag, v, nullptr);
        for (int t = 1; t < 10; t++) {
            fused_f16_kernel<<<dim3(NCH, B_), dim3(256), 0, stream>>>(
                mh, v, P, flag, Tbuf, stats);
            combine_kernel<<<dim3(B_), dim3(256), 0, stream>>>(Tbuf, stats, P, flag, v,
                                                               (t == 9) ? out : nullptr);
        }
    } else {
        for (int t = 0; t < 10; t++) {
            fused_f32_kernel<false><<<dim3(NCH, B_), dim3(256), 0, stream>>>(
                means, v, P, flag, nullptr, Tbuf, stats);
            combine_kernel<<<dim3(B_), dim3(256), 0, stream>>>(Tbuf, stats, P, flag, v,
                                                               (t == 9) ? out : nullptr);
        }
    }
}